// Round 17
// baseline (329.022 us; speedup 1.0000x reference)
//
#include <hip/hip_runtime.h>
#include <math.h>

#define NPATH 8192
#define NT    2048
#define NCF   6                 // even/odd coeffs each (deg 5 in y; full deg 11)
#define CPAD  16                // padded v2f stride per path
#define LM    (-3.75f)          // lv-range center  (lv in [-7, -0.5])
#define LR    (3.25f)           // lv-range half-width
#define SFX   2.8853900817779268f   // 2*log2(e)
#define LFX   1.4426950408889634f   // log2(e)

typedef float v2f __attribute__((ext_vector_type(2)));
typedef float v4f __attribute__((ext_vector_type(4)));

// ws float layout
#define W2P_F   0        // v2f w2pairs[k*32+j] = {W2dr[j][k], W2df[j][k]}  (2048 floats)
#define W1VP_F  2048     // v2f w1v pairs [32]
#define W3P_F   2112     // v2f w3 pairs  [32]
#define B2P_F   2176     // v2f b2 pairs  [32]
#define CST_F   2240     // b3dr, b3df, dt
#define CTAB_B  16384    // byte offset: v2f ctab[path][CPAD] = {mE0..mE5, mO0..mO5}

// TM[i][k] = coefficient of y^k in T_i(y), i,k in [0,5] (row-major, 6x6)
__device__ const float TMAT[36] = {
  1,0,0,0,0,0,
  0,1,0,0,0,0,
  -1,0,2,0,0,0,
  0,-3,0,4,0,0,
  1,0,-8,0,8,0,
  0,5,0,-20,0,16
};

__device__ __forceinline__ v2f vsplat(float x) { return (v2f){x, x}; }
__device__ __forceinline__ v2f vfma(v2f a, v2f b, v2f c) { return __builtin_elementwise_fma(a, b, c); }

__device__ __forceinline__ float tanh1(float z) {   // tanh(z) via exp2
    float e = __builtin_amdgcn_exp2f(SFX * z);
    return fmaf(__builtin_amdgcn_rcpf(1.0f + e), -2.0f, 1.0f);
}
__device__ __forceinline__ float sig1(float z) {    // sigmoid(z)
    float e = __builtin_amdgcn_exp2f(-LFX * z);
    return __builtin_amdgcn_rcpf(1.0f + e);
}
__device__ __forceinline__ v2f tanh2(v2f z) {
    v2f r; r.x = tanh1(z.x); r.y = tanh1(z.y); return r;
}

__global__ void prep_kernel(const float* __restrict__ drw1,
                            const float* __restrict__ drw2, const float* __restrict__ drb2,
                            const float* __restrict__ drw3, const float* __restrict__ drb3,
                            const float* __restrict__ dfw1,
                            const float* __restrict__ dfw2, const float* __restrict__ dfb2,
                            const float* __restrict__ dfw3, const float* __restrict__ dfb3,
                            const float* __restrict__ dtp, float* __restrict__ ws)
{
    int tid = threadIdx.x;
    for (int idx = tid; idx < 1024; idx += 256) {
        int k = idx >> 5, j = idx & 31;
        ws[W2P_F + 2 * idx]     = drw2[j * 32 + k];   // W2[j][k] pairs, k-major
        ws[W2P_F + 2 * idx + 1] = dfw2[j * 32 + k];
    }
    if (tid < 32) {
        ws[W1VP_F + 2 * tid]     = drw1[tid * 16 + 15];
        ws[W1VP_F + 2 * tid + 1] = dfw1[tid * 16 + 15];
        ws[W3P_F + 2 * tid]      = drw3[tid];
        ws[W3P_F + 2 * tid + 1]  = dfw3[tid];
        ws[B2P_F + 2 * tid]      = drb2[tid];
        ws[B2P_F + 2 * tid + 1]  = dfb2[tid];
    }
    if (tid == 0) {
        ws[CST_F]     = drb3[0];
        ws[CST_F + 1] = dfb3[0];
        ws[CST_F + 2] = dtp[0];
    }
}

// One 64-lane wave per path. Lane j evaluates both nets at Cheb node
// x_j = cos((j+.5)pi/64); even/odd split via shfl_xor(63); 32-lane DCT
// butterflies give Cheb coeffs of E(y),O(y) (deg 5 each); per-lane
// Cheb->monomial conversion. Coeffs prescaled by 1/LR (x-space state).
// O_F gets +1 on its constant term so the scan update is a single fma:
// x' = (E_F + x*(O_F+1)) + dw*(E_G + x*O_G).
__global__ __launch_bounds__(64) void build_kernel(
    const float* __restrict__ sig,
    const float* __restrict__ drw1, const float* __restrict__ drb1,
    const float* __restrict__ dfw1, const float* __restrict__ dfb1,
    const float* __restrict__ wconst, v2f* __restrict__ ctab)
{
    const int p = blockIdx.x;
    const int j = threadIdx.x;
    __shared__ v2f spv[32];            // pre pairs {dr, df} per hidden unit
    {
        int u = j & 31, net = j >> 5;
        const float* w1 = net ? dfw1 : drw1;
        const float* b1 = net ? dfb1 : drb1;
        float acc = b1[u];
#pragma unroll
        for (int m = 0; m < 15; ++m) acc = fmaf(sig[p * 15 + m], w1[u * 16 + m], acc);
        ((float*)spv)[2 * u + net] = acc;
    }
    __syncthreads();

    const float th = ((float)j + 0.5f) * (float)(M_PI / 64.0);
    const float xj = __cosf(th);
    const float v  = (LM + LR * xj) + 4.0f;        // v = lv + 4 at this node

    const v2f* __restrict__ w2p  = (const v2f*)(wconst + W2P_F);
    const v2f* __restrict__ w1vp = (const v2f*)(wconst + W1VP_F);
    const v2f* __restrict__ w3p  = (const v2f*)(wconst + W3P_F);
    const v2f* __restrict__ b2p  = (const v2f*)(wconst + B2P_F);

    v2f z3 = (v2f){wconst[CST_F], wconst[CST_F + 1]};

#pragma unroll
    for (int c = 0; c < 2; ++c) {          // two chunks of 16 output units
        v2f acc[16];
#pragma unroll
        for (int q = 0; q < 16; ++q) acc[q] = b2p[c * 16 + q];

#pragma unroll 8
        for (int k = 0; k < 32; ++k) {     // h recomputed per chunk
            v2f pre = spv[k];
            v2f z   = vfma(vsplat(v), w1vp[k], pre);
            v2f h   = tanh2(z);
            const v2f* col = w2p + k * 32 + c * 16;   // uniform -> s_load
#pragma unroll
            for (int q = 0; q < 16; ++q) acc[q] = vfma(col[q], h, acc[q]);
        }
#pragma unroll
        for (int q = 0; q < 16; ++q) {
            v2f a2 = tanh2(acc[q]);
            z3 = vfma(w3p[c * 16 + q], a2, z3);
        }
    }

    float dt = wconst[CST_F + 2];
    v2f Fj;
    Fj.x = 3.0f * tanh1(z3.x) * dt * (1.0f / LR);  // F = drift*dt/LR  (x-space)
    Fj.y = (sig1(z3.y) + 0.1f) * (1.0f / LR);      // G = diffusion/LR (x-space)

    // even/odd split: E = (F(x)+F(-x))/2, O = (F(x)-F(-x))/(2x); partner
    // lane is j^63 (x -> -x).
    v2f Fp;
    Fp.x = __shfl_xor(Fj.x, 63);
    Fp.y = __shfl_xor(Fj.y, 63);
    v2f E = (Fj + Fp) * 0.5f;
    float rx = 0.5f * __builtin_amdgcn_rcpf(xj);
    v2f O = (Fj - Fp) * vsplat(rx);

    // y-nodes: jj = j (half0) / 63-j (half1); theta2 = (jj+.5)pi/32.
    int jj = (j < 32) ? j : 63 - j;
    float th2 = ((float)jj + 0.5f) * (float)(M_PI / 32.0);

    v2f de[NCF], dq[NCF];
#pragma unroll
    for (int k = 0; k < NCF; ++k) {
        float ck = __cosf((float)k * th2);
        v2f tE = E * vsplat(ck);
        v2f tO = O * vsplat(ck);
#pragma unroll
        for (int m = 1; m < 32; m <<= 1) {         // 32-lane butterflies (halves independent)
            tE.x += __shfl_xor(tE.x, m); tE.y += __shfl_xor(tE.y, m);
            tO.x += __shfl_xor(tO.x, m); tO.y += __shfl_xor(tO.y, m);
        }
        float s = (k == 0) ? (1.0f / 32.0f) : (2.0f / 32.0f);
        de[k] = tE * vsplat(s);
        dq[k] = tO * vsplat(s);
    }

    // Cheb -> monomial: lane kk computes m_kk = sum_i d_i * TM[i][kk].
    // Lanes 0..5 -> E coeffs, lanes 16..21 -> O coeffs.
    int kk = j & 15; if (kk > 5) kk = 5;
    v2f m = vsplat(0.0f);
#pragma unroll
    for (int i = 0; i < NCF; ++i) {
        float a = TMAT[i * 6 + kk];
        m = vfma((j < 16) ? de[i] : dq[i], vsplat(a), m);
    }
    if (j == 16) m.x += 1.0f;                      // fold "+x" into O_F constant term
    if (j < 6)                  ctab[(size_t)p * CPAD + j]            = m;
    else if (j >= 16 && j < 22) ctab[(size_t)p * CPAD + 6 + (j - 16)] = m;
}

// TWO paths per lane (p and p+64): two independent recurrence chains
// interleaved in one thread so chain-A's fma-latency stalls are filled by
// chain-B's instructions (machine is otherwise 1 wave/SIMD idle). All
// coeffs named + asm-pinned; no LDS; Estrin E/O; med3 clamp; exp2+store
// off-chain; per-path 16-step dW register pipeline.
__global__ __launch_bounds__(64) __attribute__((amdgpu_waves_per_eu(1, 2)))
void scan_kernel(
    const float* __restrict__ init_var,
    const float* __restrict__ dW,
    const float* __restrict__ ws,
    float* __restrict__ out)
{
    const int lane  = threadIdx.x;
    const int pA    = blockIdx.x * 128 + lane;     // path A
    const int pB    = pA + 64;                     // path B
    const v2f* __restrict__ ctA = (const v2f*)((const char*)ws + CTAB_B) + (size_t)pA * CPAD;
    const v2f* __restrict__ ctB = (const v2f*)((const char*)ws + CTAB_B) + (size_t)pB * CPAD;

    v2f ea0 = ctA[0], ea1 = ctA[1], ea2 = ctA[2], ea3 = ctA[3], ea4 = ctA[4], ea5 = ctA[5];
    v2f oa0 = ctA[6], oa1 = ctA[7], oa2 = ctA[8], oa3 = ctA[9], oa4 = ctA[10], oa5 = ctA[11];
    v2f eb0 = ctB[0], eb1 = ctB[1], eb2 = ctB[2], eb3 = ctB[3], eb4 = ctB[4], eb5 = ctB[5];
    v2f ob0 = ctB[6], ob1 = ctB[7], ob2 = ctB[8], ob3 = ctB[9], ob4 = ctB[10], ob5 = ctB[11];
    asm volatile("" : "+v"(ea0), "+v"(ea1), "+v"(ea2), "+v"(ea3), "+v"(ea4), "+v"(ea5));
    asm volatile("" : "+v"(oa0), "+v"(oa1), "+v"(oa2), "+v"(oa3), "+v"(oa4), "+v"(oa5));
    asm volatile("" : "+v"(eb0), "+v"(eb1), "+v"(eb2), "+v"(eb3), "+v"(eb4), "+v"(eb5));
    asm volatile("" : "+v"(ob0), "+v"(ob1), "+v"(ob2), "+v"(ob3), "+v"(ob4), "+v"(ob5));

    float lvA = logf(fminf(fmaxf(init_var[pA], 0.005f), 0.2f));
    float lvB = logf(fminf(fmaxf(init_var[pB], 0.005f), 0.2f));
    float xA = fmaf(lvA, 1.0f / LR, -LM / LR);
    float xB = fmaf(lvB, 1.0f / LR, -LM / LR);
    const float K1 = LFX * LR;                     // ev = exp2(K1*x + K0)
    const float K0 = LFX * LM;
    const float* __restrict__ dwA = dW + (size_t)pA * NT;
    const float* __restrict__ dwB = dW + (size_t)pB * NT;
    float* __restrict__ outA = out + pA;
    float* __restrict__ outB = out + pB;

    auto STEPA = [&](float dw, int tt) {
        float y  = fmaf(xA + xA, xA, -1.0f);
        float y2 = y * y;
        v2f yv = vsplat(y), y2v = vsplat(y2);
        v2f eP = vfma(yv, ea1, ea0);
        v2f eQ = vfma(yv, ea3, ea2);
        v2f eR = vfma(yv, ea5, ea4);
        v2f oP = vfma(yv, oa1, oa0);
        v2f oQ = vfma(yv, oa3, oa2);
        v2f oR = vfma(yv, oa5, oa4);
        float y4 = y2 * y2;
        v2f y4v = vsplat(y4);
        v2f bE = vfma(y2v, eQ, eP);  bE = vfma(y4v, eR, bE);
        v2f bO = vfma(y2v, oQ, oP);  bO = vfma(y4v, oR, bO);
        v2f val = vfma(vsplat(xA), bO, bE);
        xA = fmaf(val.y, dw, val.x);
        xA = __builtin_amdgcn_fmed3f(xA, -1.0f, 1.0f);
        float ev = __builtin_amdgcn_exp2f(fmaf(xA, K1, K0));
        __builtin_nontemporal_store(ev, outA + (size_t)tt * NPATH);
    };
    auto STEPB = [&](float dw, int tt) {
        float y  = fmaf(xB + xB, xB, -1.0f);
        float y2 = y * y;
        v2f yv = vsplat(y), y2v = vsplat(y2);
        v2f eP = vfma(yv, eb1, eb0);
        v2f eQ = vfma(yv, eb3, eb2);
        v2f eR = vfma(yv, eb5, eb4);
        v2f oP = vfma(yv, ob1, ob0);
        v2f oQ = vfma(yv, ob3, ob2);
        v2f oR = vfma(yv, ob5, ob4);
        float y4 = y2 * y2;
        v2f y4v = vsplat(y4);
        v2f bE = vfma(y2v, eQ, eP);  bE = vfma(y4v, eR, bE);
        v2f bO = vfma(y2v, oQ, oP);  bO = vfma(y4v, oR, bO);
        v2f val = vfma(vsplat(xB), bO, bE);
        xB = fmaf(val.y, dw, val.x);
        xB = __builtin_amdgcn_fmed3f(xB, -1.0f, 1.0f);
        float ev = __builtin_amdgcn_exp2f(fmaf(xB, K1, K0));
        __builtin_nontemporal_store(ev, outB + (size_t)tt * NPATH);
    };

    // 16-step-deep dW register pipelines, one per path
    v4f a0 = *(const v4f*)(dwA + 0), a1 = *(const v4f*)(dwA + 4);
    v4f a2 = *(const v4f*)(dwA + 8), a3 = *(const v4f*)(dwA + 12);
    v4f b0 = *(const v4f*)(dwB + 0), b1 = *(const v4f*)(dwB + 4);
    v4f b2 = *(const v4f*)(dwB + 8), b3 = *(const v4f*)(dwB + 12);
    for (int t = 0; t < NT; t += 4) {
        v4f curA = a0, curB = b0;
        a0 = a1; a1 = a2; a2 = a3;
        b0 = b1; b1 = b2; b2 = b3;
        if (t + 16 < NT) {
            a3 = *(const v4f*)(dwA + t + 16);
            b3 = *(const v4f*)(dwB + t + 16);
        }
        STEPA(curA.x, t);     STEPB(curB.x, t);
        STEPA(curA.y, t + 1); STEPB(curB.y, t + 1);
        STEPA(curA.z, t + 2); STEPB(curB.z, t + 2);
        STEPA(curA.w, t + 3); STEPB(curB.w, t + 3);
    }
}

extern "C" void kernel_launch(void* const* d_in, const int* in_sizes, int n_in,
                              void* d_out, int out_size, void* d_ws, size_t ws_size,
                              hipStream_t stream) {
    const float* init_var = (const float*)d_in[0];
    const float* sig      = (const float*)d_in[1];
    const float* dW       = (const float*)d_in[2];
    const float* dtp      = (const float*)d_in[3];
    const float* drw1     = (const float*)d_in[4];
    const float* drb1     = (const float*)d_in[5];
    const float* drw2     = (const float*)d_in[6];
    const float* drb2     = (const float*)d_in[7];
    const float* drw3     = (const float*)d_in[8];
    const float* drb3     = (const float*)d_in[9];
    const float* dfw1     = (const float*)d_in[10];
    const float* dfb1     = (const float*)d_in[11];
    const float* dfw2     = (const float*)d_in[12];
    const float* dfb2     = (const float*)d_in[13];
    const float* dfw3     = (const float*)d_in[14];
    const float* dfb3     = (const float*)d_in[15];
    float* out = (float*)d_out;
    float* ws  = (float*)d_ws;

    hipLaunchKernelGGL(prep_kernel, dim3(1), dim3(256), 0, stream,
                       drw1, drw2, drb2, drw3, drb3,
                       dfw1, dfw2, dfb2, dfw3, dfb3, dtp, ws);
    hipLaunchKernelGGL(build_kernel, dim3(NPATH), dim3(64), 0, stream,
                       sig, drw1, drb1, dfw1, dfb1,
                       ws, (v2f*)((char*)ws + CTAB_B));
    hipLaunchKernelGGL(scan_kernel, dim3(NPATH / 128), dim3(64), 0, stream,
                       init_var, dW, ws, out);
}